// Round 1
// baseline (86.697 us; speedup 1.0000x reference)
//
#include <hip/hip_runtime.h>
#include <math.h>

// KAN dense layer, MI355X. N_IN=N_OUT=128, K=3, G=8, BATCH=512.
// v8: single fused kernel. v7's w_pack dispatch + 384 KB workspace round-trip
//     removed; each wave computes its 6 W fragments in-register from
//     cbasis/cspl/cres (48 values/thread, magic-div k->(i,g) decode,
//     predicated cres select for slot 11). No d_ws use at all -> the 268 MB
//     workspace re-poison fill (40 us @ 84% HBM, dominant dispatch in v7
//     rocprof) is no longer semantically needed by us.
//     Structure otherwise v7: 512 thr = 8 waves, wave owns K/8=192 (6 MFMA),
//     A-build 4 iters/thread, 16x16x32 bf16 MFMA, 8-partial LDS reduce.
#define N_IN  128
#define N_OUT 128
#define BATCH 512
#define NK    11
#define TBV   16
#define TOV   16
#define KTOT  1536           // 128 * 12
#define ASTR  1544           // shorts per A LDS row (1536 + 8 pad)

typedef float f32x4  __attribute__((ext_vector_type(4)));
typedef short bf16x8 __attribute__((ext_vector_type(8)));
typedef unsigned long long u64;

__device__ __forceinline__ unsigned short f2bf(float f) {   // RNE fp32->bf16
    unsigned u = __float_as_uint(f);
    u += 0x7FFFu + ((u >> 16) & 1u);
    return (unsigned short)(u >> 16);
}

__global__ __launch_bounds__(512) void kan_kernel(
    const float* __restrict__ x,              // [512][128]
    const float* __restrict__ cbasis,         // [16384][11]
    const float* __restrict__ cspl,           // [16384]
    const float* __restrict__ cres,           // [16384]
    const float* __restrict__ bias,           // [128]
    float* __restrict__ y)                    // [512][128]
{
    __shared__ short sA[TBV * ASTR];          // 49,408 B
    __shared__ float sAcc[8 * 256];           //  8,192 B

    const int b0 = blockIdx.x * TBV;          // 32 blocks in x
    const int o0 = blockIdx.y * TOV;          // 8 blocks in y
    const int t  = threadIdx.x;
    const int w  = t >> 6;                    // wave 0..7: owns K [192w,192w+192)
    const int l  = t & 63;
    const int mn = l & 15;                    // MFMA row (m for A, n for B)
    const int kq = (l >> 4) * 8;              // k sub-offset within 32-k step

    // ---- x loads first: 4 coalesced dwords, one vmcnt wait later ----
    float xv[4];
    #pragma unroll
    for (int it = 0; it < 4; ++it) {
        const int p = t + it * 512;
        xv[it] = x[(b0 + (p >> 7)) * N_IN + (p & 127)];
    }

    // ---- build this wave's 6 W fragments in-register (was w_pack + reload) ----
    // W[o][i*12+g] = cspl[e]*cbasis[e][g] (g<11), slot 11 = cres[e]; e=o*128+i.
    // Thread covers k = w*192 + kq + s*32 + j, j=0..7, s=0..5.
    const int o = o0 + mn;
    const float* __restrict__ cb = cbasis + (size_t)o * (128 * NK);
    const float* __restrict__ cs = cspl + o * 128;
    const float* __restrict__ cr = cres + o * 128;
    bf16x8 wf[6];
    #pragma unroll
    for (int s = 0; s < 6; ++s) {
        const int k0 = w * 192 + kq + s * 32;
        #pragma unroll
        for (int j = 0; j < 8; ++j) {
            const int k = k0 + j;
            const int i = k / 12;              // magic-mul, const divisor
            const int g = k - i * 12;
            float v;
            if (g < NK) v = cs[i] * cb[i * NK + g];   // exec-masked: no OOB
            else        v = cr[i];
            wf[s][j] = (short)f2bf(v);
        }
    }

    // ---- build A slab: 16 b x 128 i, 4 per thread ----
    #pragma unroll
    for (int it = 0; it < 4; ++it) {
        const int p = t + it * 512;
        const int b = p >> 7, i = p & 127;
        const float v = xv[it];
        const float u = (v + 1.75f) * 4.0f;              // u in [3,11)
        float jf = floorf(u);
        jf = fminf(fmaxf(jf, 3.0f), 10.0f);
        const float tt = u - jf;
        const float omt = 1.0f - tt;
        const float t2 = tt * tt, t3 = t2 * tt;
        const float B0 = omt * omt * omt * (1.0f / 6.0f);
        const float B1 = (3.0f * t3 - 6.0f * t2 + 4.0f) * (1.0f / 6.0f);
        const float B2 = (-3.0f * t3 + 3.0f * t2 + 3.0f * tt + 1.0f) * (1.0f / 6.0f);
        const float B3 = t3 * (1.0f / 6.0f);
        const int base = (int)jf - 3;                    // 0..7
        const float sig = 1.0f / (1.0f + __expf(-v));
        // 4 bf16 -> u64, placed at bit offset base*16 in the 192-bit strip
        const u64 v4 = (u64)f2bf(B0) | ((u64)f2bf(B1) << 16)
                     | ((u64)f2bf(B2) << 32) | ((u64)f2bf(B3) << 48);
        const int sh = base * 16;                        // 0..112
        u64 q0, q1, q2;
        if (sh < 64) {
            q0 = v4 << sh;
            q1 = sh ? (v4 >> (64 - sh)) : 0ull;
            q2 = 0ull;
        } else {
            q0 = 0ull;
            q1 = v4 << (sh - 64);
            q2 = (sh > 64) ? (v4 >> (128 - sh)) : 0ull;
        }
        q2 |= (u64)f2bf(v * sig) << 48;                  // silu -> slot 11
        u64* dst = (u64*)&sA[b * ASTR + i * 12];         // 8B-aligned
        dst[0] = q0; dst[1] = q1; dst[2] = q2;
    }
    __syncthreads();

    // ---- MFMA: 6 steps of 16x16x32 over this wave's K range ----
    f32x4 acc = {0.f, 0.f, 0.f, 0.f};
    const short* aB = &sA[mn * ASTR + w * 192 + kq];     // 16B-aligned
    #pragma unroll
    for (int s = 0; s < 6; ++s) {
        bf16x8 af = *(const bf16x8*)(aB + s * 32);       // ds_read_b128
        acc = __builtin_amdgcn_mfma_f32_16x16x32_bf16(af, wf[s], acc, 0, 0, 0);
    }

    // ---- reduce 8 wave-partials; C layout: col=lane&15, row=(lane>>4)*4+r ----
    #pragma unroll
    for (int r = 0; r < 4; ++r)
        sAcc[w * 256 + ((l >> 4) * 4 + r) * 16 + mn] = acc[r];
    __syncthreads();
    if (t < 256) {
        const int m2 = t >> 4, n2 = t & 15;
        float sum = bias[o0 + n2];
        #pragma unroll
        for (int ww = 0; ww < 8; ++ww) sum += sAcc[ww * 256 + t];
        y[(b0 + m2) * N_OUT + (o0 + n2)] = sum;
    }
}

extern "C" void kernel_launch(void* const* d_in, const int* in_sizes, int n_in,
                              void* d_out, int out_size, void* d_ws, size_t ws_size,
                              hipStream_t stream) {
    const float* x      = (const float*)d_in[0];
    // d_in[1] = knots: unused — uniform grid known in closed form
    const float* cbasis = (const float*)d_in[2];
    const float* cspl   = (const float*)d_in[3];
    const float* cres   = (const float*)d_in[4];
    const float* bias   = (const float*)d_in[5];
    float* y = (float*)d_out;
    (void)d_ws; (void)ws_size;                // no workspace: no re-poison dependency

    dim3 grid(BATCH / TBV, N_OUT / TOV);      // 32 x 8 = 256 blocks, 1/CU
    kan_kernel<<<grid, 512, 0, stream>>>(x, cbasis, cspl, cres, bias, y);
}

// Round 2
// 67.570 us; speedup vs baseline: 1.2831x; 1.2831x over previous
//
#include <hip/hip_runtime.h>
#include <math.h>

// KAN dense layer, MI355X. N_IN=N_OUT=128, K=3, G=8, BATCH=512.
// v9: single fused kernel, W packed per-block into LDS with COALESCED loads
//     (v8's regression was 48 scattered gathers/thread for the in-register
//     W build). The 16 cbasis rows a block needs are a contiguous
//     22528-float range -> 11 float4 loads/thread, f/11 decode, bf16
//     scalar LDS writes (consecutive lanes -> consecutive shorts, ~2-way
//     bank aliasing = free). B-fragments read from LDS via ds_read_b128.
//     One dispatch node total: saves v7's second node + w2 HBM round-trip.
//     Workspace poison fill (40.5 us, unconditional) is the harness floor.
#define N_IN  128
#define N_OUT 128
#define BATCH 512
#define NK    11
#define TBV   16
#define TOV   16
#define ASTR  1544           // shorts per LDS row (1536 + 8 pad)
#define WSTR  1544

typedef float f32x4  __attribute__((ext_vector_type(4)));
typedef short bf16x8 __attribute__((ext_vector_type(8)));
typedef unsigned long long u64;

__device__ __forceinline__ unsigned short f2bf(float f) {   // RNE fp32->bf16
    unsigned u = __float_as_uint(f);
    u += 0x7FFFu + ((u >> 16) & 1u);
    return (unsigned short)(u >> 16);
}

__global__ __launch_bounds__(512) void kan_kernel(
    const float* __restrict__ x,              // [512][128]
    const float* __restrict__ cbasis,         // [16384][11]
    const float* __restrict__ cspl,           // [16384]
    const float* __restrict__ cres,           // [16384]
    const float* __restrict__ bias,           // [128]
    float* __restrict__ y)                    // [512][128]
{
    __shared__ short sW[TOV * WSTR];          // 49,408 B  (W tile, bf16)
    __shared__ short sA[TBV * ASTR];          // 49,408 B  (A slab, bf16)
    __shared__ float sAcc[8 * 256];           //  8,192 B  -> 106.9 KB total

    const int b0 = blockIdx.x * TBV;          // 32 blocks in x
    const int o0 = blockIdx.y * TOV;          // 8 blocks in y
    const int t  = threadIdx.x;
    const int w  = t >> 6;                    // wave 0..7: owns K [192w,192w+192)
    const int l  = t & 63;
    const int mn = l & 15;                    // MFMA row (m for A, n for B)
    const int kq = (l >> 4) * 8;              // k sub-offset within 32-k step

    // ---- x loads first: 4 coalesced dwords ----
    float xv[4];
    #pragma unroll
    for (int it = 0; it < 4; ++it) {
        const int p = t + it * 512;
        xv[it] = x[(b0 + (p >> 7)) * N_IN + (p & 127)];
    }

    // ---- W pack into LDS, coalesced ----
    // Block needs edges e in [o0*128, (o0+16)*128): contiguous 2048*11 floats.
    // sW[o2][i*12+g] = f2bf(cspl[e]*cbasis[e][g]); slot 11 = f2bf(cres[e]).
    const float4* __restrict__ cb4 = (const float4*)(cbasis + (size_t)o0 * 128 * NK);
    const float*  __restrict__ csb = cspl + o0 * 128;
    const float*  __restrict__ crb = cres + o0 * 128;
    #pragma unroll
    for (int it = 0; it < 11; ++it) {
        const int q = t + it * 512;           // 0..5631 float4s
        const float4 v4 = cb4[q];
        const int f0 = q * 4;
        const float vj[4] = {v4.x, v4.y, v4.z, v4.w};
        #pragma unroll
        for (int j = 0; j < 4; ++j) {
            const int f = f0 + j;             // flat idx: e*11+g
            const int e = f / 11;             // magic-mul, const divisor
            const int g = f - e * 11;
            sW[(e >> 7) * WSTR + (e & 127) * 12 + g] = (short)f2bf(vj[j] * csb[e]);
        }
    }
    #pragma unroll
    for (int it = 0; it < 4; ++it) {          // residual weights -> slot 11
        const int e = t + it * 512;           // 0..2047
        sW[(e >> 7) * WSTR + (e & 127) * 12 + 11] = (short)f2bf(crb[e]);
    }

    // ---- build A slab: 16 b x 128 i, 4 per thread ----
    #pragma unroll
    for (int it = 0; it < 4; ++it) {
        const int p = t + it * 512;
        const int b = p >> 7, i = p & 127;
        const float v = xv[it];
        const float u = (v + 1.75f) * 4.0f;              // u in [3,11)
        float jf = floorf(u);
        jf = fminf(fmaxf(jf, 3.0f), 10.0f);
        const float tt = u - jf;
        const float omt = 1.0f - tt;
        const float t2 = tt * tt, t3 = t2 * tt;
        const float B0 = omt * omt * omt * (1.0f / 6.0f);
        const float B1 = (3.0f * t3 - 6.0f * t2 + 4.0f) * (1.0f / 6.0f);
        const float B2 = (-3.0f * t3 + 3.0f * t2 + 3.0f * tt + 1.0f) * (1.0f / 6.0f);
        const float B3 = t3 * (1.0f / 6.0f);
        const int base = (int)jf - 3;                    // 0..7
        const float sig = 1.0f / (1.0f + __expf(-v));
        // 4 bf16 -> u64, placed at bit offset base*16 in the 192-bit strip
        const u64 v4 = (u64)f2bf(B0) | ((u64)f2bf(B1) << 16)
                     | ((u64)f2bf(B2) << 32) | ((u64)f2bf(B3) << 48);
        const int sh = base * 16;                        // 0..112
        u64 q0, q1, q2;
        if (sh < 64) {
            q0 = v4 << sh;
            q1 = sh ? (v4 >> (64 - sh)) : 0ull;
            q2 = 0ull;
        } else {
            q0 = 0ull;
            q1 = v4 << (sh - 64);
            q2 = (sh > 64) ? (v4 >> (128 - sh)) : 0ull;
        }
        q2 |= (u64)f2bf(v * sig) << 48;                  // silu -> slot 11
        u64* dst = (u64*)&sA[b * ASTR + i * 12];         // 8B-aligned
        dst[0] = q0; dst[1] = q1; dst[2] = q2;
    }
    __syncthreads();

    // ---- MFMA: 6 steps of 16x16x32 over this wave's K range ----
    f32x4 acc = {0.f, 0.f, 0.f, 0.f};
    const short* aB = &sA[mn * ASTR + w * 192 + kq];     // 16B-aligned
    const short* wB = &sW[mn * WSTR + w * 192 + kq];     // 16B-aligned
    #pragma unroll
    for (int s = 0; s < 6; ++s) {
        bf16x8 af = *(const bf16x8*)(aB + s * 32);       // ds_read_b128
        bf16x8 wf = *(const bf16x8*)(wB + s * 32);       // ds_read_b128
        acc = __builtin_amdgcn_mfma_f32_16x16x32_bf16(af, wf, acc, 0, 0, 0);
    }

    // ---- reduce 8 wave-partials; C layout: col=lane&15, row=(lane>>4)*4+r ----
    #pragma unroll
    for (int r = 0; r < 4; ++r)
        sAcc[w * 256 + ((l >> 4) * 4 + r) * 16 + mn] = acc[r];
    __syncthreads();
    if (t < 256) {
        const int m2 = t >> 4, n2 = t & 15;
        float sum = bias[o0 + n2];
        #pragma unroll
        for (int ww = 0; ww < 8; ++ww) sum += sAcc[ww * 256 + t];
        y[(b0 + m2) * N_OUT + (o0 + n2)] = sum;
    }
}

extern "C" void kernel_launch(void* const* d_in, const int* in_sizes, int n_in,
                              void* d_out, int out_size, void* d_ws, size_t ws_size,
                              hipStream_t stream) {
    const float* x      = (const float*)d_in[0];
    // d_in[1] = knots: unused — uniform grid known in closed form
    const float* cbasis = (const float*)d_in[2];
    const float* cspl   = (const float*)d_in[3];
    const float* cres   = (const float*)d_in[4];
    const float* bias   = (const float*)d_in[5];
    float* y = (float*)d_out;
    (void)d_ws; (void)ws_size;

    dim3 grid(BATCH / TBV, N_OUT / TOV);      // 32 x 8 = 256 blocks, 1/CU
    kan_kernel<<<grid, 512, 0, stream>>>(x, cbasis, cspl, cres, bias, y);
}